// Round 4
// baseline (409.356 us; speedup 1.0000x reference)
//
#include <hip/hip_runtime.h>

// QJLKeyCache: out = softmax_rows(EST * norms[n] * (Q @ S^T) @ K^T)
// B=2048, D=128, M=256, NKEYS=32768.
// Round 7 == round 5 resubmission (4x GPU acquisition timeout; structure
// still unmeasured — no blind changes stacked on top).
//  - S1 (stats_kernel): m97-class GEMM core, epilogue = per-(row,cb)
//    max + sum(exp) only. No LDS transpose, no score stores (-128 MB write).
//  - combine: 256 cb stats -> per-row C = M + ln(L)  (softmax as exp(s - C)).
//  - S2 (out_kernel): recompute the GEMM, write exp(s - C) straight to fp32
//    out (-128 MB read vs old scores pipeline). fp32 stores are 64B-sector
//    aligned segments -> no partial-sector penalty, no transpose needed.
// Cost: +34.4 GF MFMA (~40 us) for -256 MB HBM round-trip and one fewer
// streaming kernel.

#define NB 2048
#define DD 128
#define MM 256
#define NK 32768
// sqrt(pi/2)/256
#define EST_CONST 4.8957583489668673e-03f

typedef _Float16 half8 __attribute__((ext_vector_type(8)));
typedef _Float16 half4v __attribute__((ext_vector_type(4)));
typedef float floatx4 __attribute__((ext_vector_type(4)));

__device__ __forceinline__ void async16(const void* g, void* l) {
    __builtin_amdgcn_global_load_lds(
        (const __attribute__((address_space(1))) unsigned int*)g,
        (__attribute__((address_space(3))) unsigned int*)l,
        16, 0, 0);
}

// K1: proj[b][m] = sum_d query[b][d]*sketch[m][d], stored fp16.
__global__ void proj_kernel(const float* __restrict__ query,
                            const float* __restrict__ sketch,
                            _Float16* __restrict__ proj) {
    __shared__ float q[DD];
    const int b = blockIdx.x;
    const int t = threadIdx.x;
    if (t < DD) q[t] = query[b * DD + t];
    __syncthreads();
    const float* srow = sketch + t * DD;   // t = m in [0,256)
    float acc = 0.f;
#pragma unroll
    for (int d = 0; d < DD; d += 4) {
        float4 s4 = *(const float4*)(srow + d);
        acc += s4.x * q[d] + s4.y * q[d + 1] + s4.z * q[d + 2] + s4.w * q[d + 3];
    }
    proj[b * MM + t] = (_Float16)acc;
}

// K2: cached_keys fp32 (+-1) -> fp16 (exact).
__global__ void cvt_keys(const float* __restrict__ keys, _Float16* __restrict__ kh) {
    const int i = blockIdx.x * 256 + threadIdx.x;   // one float4 per thread
    float4 v = ((const float4*)keys)[i];
    half4v h;
    h.x = (_Float16)v.x; h.y = (_Float16)v.y; h.z = (_Float16)v.z; h.w = (_Float16)v.w;
    ((half4v*)kh)[i] = h;
}

// K3 (S1): 128x128 tile GEMM, BK=64, fp16 MFMA, keys as first operand.
// Epilogue: per-row block-local max + sum(exp) -> stats only. No score store.
__global__ __launch_bounds__(256, 3)
void stats_kernel(const _Float16* __restrict__ proj,   // [2048][256]
                  const _Float16* __restrict__ kh,     // [32768][256]
                  const float* __restrict__ key_norms,
                  float* __restrict__ stats_max,       // [2048][256]
                  float* __restrict__ stats_sum) {     // [2048][256]
    __shared__ __align__(16) _Float16 smem[16384];   // sQ(16KB) + sK(16KB)
    __shared__ float red[128][2];
    __shared__ float redS[128][2];
    _Float16* sQ = smem;
    _Float16* sK = smem + 8192;

    const int tid  = threadIdx.x;
    const int lane = tid & 63;
    const int wave = tid >> 6;
    const int quad = lane >> 4;
    const int lc   = lane & 15;
    const int wb   = wave >> 1;   // b-row 64-strip
    const int wn   = wave & 1;    // key-col 64-strip
    const int cb      = blockIdx.x;         // key col-block (fastest -> XCD owns keys)
    const int colBase = cb * 128;
    const int rowBase = blockIdx.y * 128;   // batch rows

    floatx4 acc[4][4];   // [ib][in]: C[b=wb*64+ib*16+lc][n=wn*64+in*16+quad*4+r]
#pragma unroll
    for (int i = 0; i < 4; i++)
#pragma unroll
        for (int j = 0; j < 4; j++) acc[i][j] = (floatx4){0.f, 0.f, 0.f, 0.f};

    // Staging: chunk c in [0,1024): LDS slot c*16B (wave-uniform + lane*16),
    // holds global (row=c>>3, seg=(c&7)^(row&7)) -- XOR swizzle balances the
    // ds_read_b128 bank pattern for the 128B row stride.
    const _Float16* gQ[4];
    const _Float16* gK[4];
    int ldsOff[4];
#pragma unroll
    for (int p = 0; p < 4; p++) {
        const int c = p * 256 + tid;
        const int row = c >> 3;
        const int seg = (c & 7) ^ (row & 7);
        gQ[p] = proj + (rowBase + row) * MM + seg * 8;
        gK[p] = kh + (colBase + row) * MM + seg * 8;
        ldsOff[p] = c * 8;
    }

    for (int k0 = 0; k0 < MM; k0 += 64) {
        __syncthreads();
#pragma unroll
        for (int p = 0; p < 4; p++) {
            async16(gQ[p] + k0, &sQ[ldsOff[p]]);
            async16(gK[p] + k0, &sK[ldsOff[p]]);
        }
        __syncthreads();
#pragma unroll
        for (int kk = 0; kk < 2; kk++) {
            const int segSel = ((kk * 4 + quad) ^ (lc & 7)) * 8;
            half8 kf[4], qf[4];
#pragma unroll
            for (int s = 0; s < 4; s++) {
                kf[s] = *(const half8*)&sK[(wn * 64 + s * 16 + lc) * 64 + segSel];
                qf[s] = *(const half8*)&sQ[(wb * 64 + s * 16 + lc) * 64 + segSel];
            }
#pragma unroll
            for (int ib = 0; ib < 4; ib++)
#pragma unroll
                for (int in = 0; in < 4; in++)
                    acc[ib][in] = __builtin_amdgcn_mfma_f32_16x16x32_f16(
                        kf[in], qf[ib], acc[ib][in], 0, 0, 0);
        }
    }

    // scale: s = EST * norm[n] * inner ; n varies with (in, quad, r)
#pragma unroll
    for (int in = 0; in < 4; in++) {
        const float4 nrm = *(const float4*)&key_norms[colBase + wn * 64 + in * 16 + quad * 4];
#pragma unroll
        for (int ib = 0; ib < 4; ib++) {
            acc[ib][in][0] *= EST_CONST * nrm.x;
            acc[ib][in][1] *= EST_CONST * nrm.y;
            acc[ib][in][2] *= EST_CONST * nrm.z;
            acc[ib][in][3] *= EST_CONST * nrm.w;
        }
    }

    // per-row (128-col block-local) max; row owned by lane lc (dup over quads)
#pragma unroll
    for (int ib = 0; ib < 4; ib++) {
        float mx = -1e30f;
#pragma unroll
        for (int in = 0; in < 4; in++)
#pragma unroll
            for (int r = 0; r < 4; r++) mx = fmaxf(mx, acc[ib][in][r]);
        mx = fmaxf(mx, __shfl_xor(mx, 16, 64));
        mx = fmaxf(mx, __shfl_xor(mx, 32, 64));
        if (quad == 0) red[wb * 64 + ib * 16 + lc][wn] = mx;
    }
    __syncthreads();   // red visible
    float mcb[4];
#pragma unroll
    for (int ib = 0; ib < 4; ib++) {
        const int rl = wb * 64 + ib * 16 + lc;
        mcb[ib] = fmaxf(red[rl][0], red[rl][1]);
    }
    // partial sums of exp(s - mcb)
#pragma unroll
    for (int ib = 0; ib < 4; ib++) {
        float sm = 0.f;
#pragma unroll
        for (int in = 0; in < 4; in++)
#pragma unroll
            for (int r = 0; r < 4; r++) sm += __expf(acc[ib][in][r] - mcb[ib]);
        sm += __shfl_xor(sm, 16, 64);
        sm += __shfl_xor(sm, 32, 64);
        if (quad == 0) redS[wb * 64 + ib * 16 + lc][wn] = sm;
    }
    __syncthreads();   // redS visible
    if (wn == 0 && quad == 0) {
#pragma unroll
        for (int ib = 0; ib < 4; ib++) {
            const int rl = wb * 64 + ib * 16 + lc;
            const int grow = rowBase + rl;
            stats_max[grow * 256 + cb] = mcb[ib];
            stats_sum[grow * 256 + cb] = redS[rl][0] + redS[rl][1];
        }
    }
}

// K4: per-row combine of 256 (m, l) -> rowC[row] = M + ln(L), so the output
// pass is a single exp(s - C). One wave per row; butterfly reduce.
__global__ void combine_stats(const float* __restrict__ smax, const float* __restrict__ ssum,
                              float* __restrict__ rowC) {
    const int lane = threadIdx.x & 63;
    const int row = blockIdx.x * 4 + (threadIdx.x >> 6);
    const float4 mv = ((const float4*)(smax + row * 256))[lane];
    float m = fmaxf(fmaxf(mv.x, mv.y), fmaxf(mv.z, mv.w));
#pragma unroll
    for (int d = 1; d < 64; d <<= 1) m = fmaxf(m, __shfl_xor(m, d, 64));
    const float4 sv = ((const float4*)(ssum + row * 256))[lane];
    float l = sv.x * __expf(mv.x - m) + sv.y * __expf(mv.y - m) +
              sv.z * __expf(mv.z - m) + sv.w * __expf(mv.w - m);
#pragma unroll
    for (int d = 1; d < 64; d <<= 1) l += __shfl_xor(l, d, 64);
    if (lane == 0) rowC[row] = m + __logf(l);   // L >= 1 always (contains exp(0))
}

// K5 (S2): recompute the identical GEMM; epilogue applies exp(s - C) and
// stores fp32 out directly. Store pattern: per wave-instruction 16 rows x
// 64B segments (64B = L2 sector, no partial-sector penalty); the 4 `in`
// iterations complete 256B contiguous per row.
__global__ __launch_bounds__(256, 3)
void out_kernel(const _Float16* __restrict__ proj,   // [2048][256]
                const _Float16* __restrict__ kh,     // [32768][256]
                const float* __restrict__ key_norms,
                const float* __restrict__ rowC,      // [2048]
                float* __restrict__ out) {           // [2048][32768]
    __shared__ __align__(16) _Float16 smem[16384];
    _Float16* sQ = smem;
    _Float16* sK = smem + 8192;

    const int tid  = threadIdx.x;
    const int lane = tid & 63;
    const int wave = tid >> 6;
    const int quad = lane >> 4;
    const int lc   = lane & 15;
    const int wb   = wave >> 1;
    const int wn   = wave & 1;
    const int cb      = blockIdx.x;
    const int colBase = cb * 128;
    const int rowBase = blockIdx.y * 128;

    floatx4 acc[4][4];
#pragma unroll
    for (int i = 0; i < 4; i++)
#pragma unroll
        for (int j = 0; j < 4; j++) acc[i][j] = (floatx4){0.f, 0.f, 0.f, 0.f};

    const _Float16* gQ[4];
    const _Float16* gK[4];
    int ldsOff[4];
#pragma unroll
    for (int p = 0; p < 4; p++) {
        const int c = p * 256 + tid;
        const int row = c >> 3;
        const int seg = (c & 7) ^ (row & 7);
        gQ[p] = proj + (rowBase + row) * MM + seg * 8;
        gK[p] = kh + (colBase + row) * MM + seg * 8;
        ldsOff[p] = c * 8;
    }

    // hoist per-row softmax constants (4 rows/thread, broadcast in 16-lane groups)
    float cRow[4];
#pragma unroll
    for (int ib = 0; ib < 4; ib++)
        cRow[ib] = rowC[rowBase + wb * 64 + ib * 16 + lc];

    for (int k0 = 0; k0 < MM; k0 += 64) {
        __syncthreads();
#pragma unroll
        for (int p = 0; p < 4; p++) {
            async16(gQ[p] + k0, &sQ[ldsOff[p]]);
            async16(gK[p] + k0, &sK[ldsOff[p]]);
        }
        __syncthreads();
#pragma unroll
        for (int kk = 0; kk < 2; kk++) {
            const int segSel = ((kk * 4 + quad) ^ (lc & 7)) * 8;
            half8 kf[4], qf[4];
#pragma unroll
            for (int s = 0; s < 4; s++) {
                kf[s] = *(const half8*)&sK[(wn * 64 + s * 16 + lc) * 64 + segSel];
                qf[s] = *(const half8*)&sQ[(wb * 64 + s * 16 + lc) * 64 + segSel];
            }
#pragma unroll
            for (int ib = 0; ib < 4; ib++)
#pragma unroll
                for (int in = 0; in < 4; in++)
                    acc[ib][in] = __builtin_amdgcn_mfma_f32_16x16x32_f16(
                        kf[in], qf[ib], acc[ib][in], 0, 0, 0);
        }
    }

    // scale (same FMA ordering as stats_kernel)
#pragma unroll
    for (int in = 0; in < 4; in++) {
        const float4 nrm = *(const float4*)&key_norms[colBase + wn * 64 + in * 16 + quad * 4];
#pragma unroll
        for (int ib = 0; ib < 4; ib++) {
            acc[ib][in][0] *= EST_CONST * nrm.x;
            acc[ib][in][1] *= EST_CONST * nrm.y;
            acc[ib][in][2] *= EST_CONST * nrm.z;
            acc[ib][in][3] *= EST_CONST * nrm.w;
        }
    }

    // out[grow][gcol] = exp(s - C), fp32, nontemporal 16B/lane
#pragma unroll
    for (int ib = 0; ib < 4; ib++) {
        const int grow = rowBase + wb * 64 + ib * 16 + lc;
        const float c = cRow[ib];
        float* orow = out + (size_t)grow * NK + colBase + wn * 64 + quad * 4;
#pragma unroll
        for (int in = 0; in < 4; in++) {
            floatx4 o;
#pragma unroll
            for (int r = 0; r < 4; r++)
                o[r] = __expf(acc[ib][in][r] - c);
            __builtin_nontemporal_store(o, (floatx4*)(orow + in * 16));
        }
    }
}

extern "C" void kernel_launch(void* const* d_in, const int* in_sizes, int n_in,
                              void* d_out, int out_size, void* d_ws, size_t ws_size,
                              hipStream_t stream) {
    const float* query  = (const float*)d_in[0];   // [2048][128]
    const float* keys   = (const float*)d_in[1];   // [32768][256] (+-1)
    const float* norms  = (const float*)d_in[2];   // [32768]
    const float* sketch = (const float*)d_in[3];   // [256][128]
    float* out = (float*)d_out;                    // [2048][32768]

    char* ws = (char*)d_ws;
    const size_t MB = 1024 * 1024;
    _Float16* kh   = (_Float16*)(ws);               // 16 MB
    _Float16* proj = (_Float16*)(ws + 16 * MB);     // 1 MB
    float* smax    = (float*)(ws + 17 * MB);        // 2 MB
    float* ssum    = (float*)(ws + 19 * MB);        // 2 MB
    float* rowC    = (float*)(ws + 21 * MB);        // 8 KB

    hipLaunchKernelGGL(proj_kernel, dim3(NB), dim3(256), 0, stream, query, sketch, proj);
    hipLaunchKernelGGL(cvt_keys, dim3(NK * MM / 4 / 256), dim3(256), 0, stream, keys, kh);
    hipLaunchKernelGGL(stats_kernel, dim3(NK / 128, NB / 128), dim3(256), 0, stream,
                       proj, kh, norms, smax, ssum);
    hipLaunchKernelGGL(combine_stats, dim3(NB / 4), dim3(256), 0, stream,
                       smax, ssum, rowC);
    hipLaunchKernelGGL(out_kernel, dim3(NK / 128, NB / 128), dim3(256), 0, stream,
                       proj, kh, norms, rowC, out);
}